// Round 8
// baseline (207.018 us; speedup 1.0000x reference)
//
#include <hip/hip_runtime.h>

// GraphSAGEConv: out_i = mean_{j in N(i)} x_j @ W_l + b_l + x_i @ W_r
// N=100000, E=1600000, D_in=D_out=64.
//
// 4 dispatches:
//   memset:   gfill[1024] u64 = 0 (8 KB)
//   prep_bin: heterogeneous (convert blocks + binning blocks), as round 7:
//             convert now writes x as 4 TRANSPOSED QUARTER-SLABS
//             xq[q][node][16 feats] bf16 (32 B/row, 3.2 MB/slab) + zeroes
//             8 dummy pad rows; binning: 32-node sub-buckets, packed-u64
//             reservation, scatter (src<<8)|(dst&255) into fixed regions.
//   gather_q: one 256-thr block per (32-node sub-bucket, feature-quarter).
//             XCD-pinned: q = (blockIdx&7)>>1 -> quarter q only on XCDs
//             {2q,2q+1}; each XCD's random gathers stay inside ONE 3.2-MB
//             slab (< 4 MB per-XCD L2) -> gathers become L2 hits.  (Round-7
//             evidence: L3-warm iterations ran at identical speed -> bound
//             by on-chip random-gather throughput, not HBM, not latency.)
//             Per block: reg-staged edge pass -> LDS hist -> padded (x8)
//             shfl scan -> place + dummy-fill (no tail code); gather 8
//             edges/wave-instr (8 lanes x dword per 32-B row), 4-step ILP;
//             butterfly-reduce (xor 8/16/32); write f32 partial means as
//             disjoint 16-feature strips DIRECTLY INTO out (no extra buf).
//   sage_gemm: 64 nodes/block: stage means-frags from out into registers,
//             __syncthreads (all means reads precede any final write), then
//             dual-GEMM via 16x mfma_f32_16x16x32_bf16 (K=128 fused),
//             self-path fragments straight from the xq slabs; overwrite out.

#define DFEAT 64
#define MAXBUCK 512                  // coarse buckets (256 nodes), N <= 131072
#define NSUB8 4096                   // 32-node sub-buckets (MAXBUCK*8)
#define SORT_CAP 1024                // LDS edge capacity (<=768 real + pad)
#define EVMAX 3                      // cap8/256 = 768/256 reg-stage depth
#define CONVB 192                    // convert blocks
#define BCHUNK 7168                  // edges per binning block (14 * 512)

typedef short bf16x8 __attribute__((ext_vector_type(8)));
typedef float f32x4 __attribute__((ext_vector_type(4)));

static __device__ __forceinline__ unsigned short f2bf(float f) {
    unsigned int u = __float_as_uint(f);
    unsigned int r = (u + 0x7FFFu + ((u >> 16) & 1u)) >> 16;   // RNE
    return (unsigned short)r;
}
static __device__ __forceinline__ float bf2f_lo(unsigned int u) {
    return __uint_as_float(u << 16);
}
static __device__ __forceinline__ float bf2f_hi(unsigned int u) {
    return __uint_as_float(u & 0xFFFF0000u);
}

// heterogeneous: convert blocks + binning blocks, one dispatch.
__launch_bounds__(512)
__global__ void prep_bin(const float* __restrict__ x,
                         const float* __restrict__ Wl,
                         const float* __restrict__ Wr,
                         const int* __restrict__ src,
                         const int* __restrict__ dst,
                         unsigned short* __restrict__ xq,
                         unsigned short* __restrict__ wl16,
                         unsigned short* __restrict__ wr16,
                         unsigned long long* __restrict__ gfill,
                         unsigned int* __restrict__ binned,
                         int nx4, int E, int nbuck, int cap, int cap8,
                         int ssh, int N) {
    __shared__ int hcnt[NSUB8];
    __shared__ int hbase[NSUB8];
    int b = blockIdx.x, t = threadIdx.x;

    // ---- convert blocks ----
    if (b < CONVB) {
        if (b == 0) {                       // zero 8 dummy pad rows per slab
            for (int i = t; i < 128; i += 512) {
                int slab = i >> 5, r = (i >> 2) & 7, c = i & 3;
                ushort4 z; z.x = 0; z.y = 0; z.z = 0; z.w = 0;
                *(ushort4*)(xq + (size_t)slab * ssh + (size_t)(N + r) * 16 + c * 4) = z;
            }
        }
        int total = 2048 + nx4;
        for (int i = b * 512 + t; i < total; i += CONVB * 512) {
            if (i < 2048) {
                const float* sp = (i < 1024) ? Wl : Wr;
                unsigned short* dp = (i < 1024) ? wl16 : wr16;
                int k = i & 1023;
                float4 v = ((const float4*)sp)[k];
                ushort4 hh;
                hh.x = f2bf(v.x); hh.y = f2bf(v.y); hh.z = f2bf(v.z); hh.w = f2bf(v.w);
                ((ushort4*)dp)[k] = hh;
            } else {
                int k = i - 2048;           // float4 index over x
                float4 v = ((const float4*)x)[k];
                ushort4 hh;
                hh.x = f2bf(v.x); hh.y = f2bf(v.y); hh.z = f2bf(v.z); hh.w = f2bf(v.w);
                int node = k >> 4, j = k & 15;
                int slab = j >> 2, col = j & 3;
                *(ushort4*)(xq + (size_t)slab * ssh + (size_t)node * 16 + col * 4) = hh;
            }
        }
        return;
    }

    // ---- binning blocks (round-7 proven) ----
    int bb = b - CONVB;
    int lo = bb * BCHUNK;
    int hi = lo + BCHUNK; if (hi > E) hi = E;

    for (int i = t; i < NSUB8; i += 512) hcnt[i] = 0;

    unsigned dv[14]; int sv[14];
    #pragma unroll
    for (int k = 0; k < 14; ++k) {
        int i = lo + t + (k << 9);
        bool ok = (i < hi);
        dv[k] = ok ? (unsigned)dst[i] : 0xFFFFFFFFu;
        sv[k] = ok ? src[i] : 0;
    }
    __syncthreads();

    #pragma unroll
    for (int k = 0; k < 14; ++k)
        if (dv[k] != 0xFFFFFFFFu) atomicAdd(&hcnt[dv[k] >> 5], 1);
    __syncthreads();

    for (int i = t; i < nbuck; i += 512) {
        int base = i * cap;
        #pragma unroll
        for (int j = 0; j < 2; ++j) {
            int s0 = 8 * i + 4 * j;
            int c0 = hcnt[s0], c1 = hcnt[s0 + 1];
            int c2 = hcnt[s0 + 2], c3 = hcnt[s0 + 3];
            unsigned long long add =  (unsigned long long)(unsigned)c0
                                   | ((unsigned long long)(unsigned)c1 << 16)
                                   | ((unsigned long long)(unsigned)c2 << 32)
                                   | ((unsigned long long)(unsigned)c3 << 48);
            if (add) {
                unsigned long long old = atomicAdd(&gfill[2 * i + j], add);
                int sb = base + (4 * j) * cap8;
                hbase[s0 + 0] = sb            + (int)( old        & 0xFFFFu);
                hbase[s0 + 1] = sb +     cap8 + (int)((old >> 16) & 0xFFFFu);
                hbase[s0 + 2] = sb + 2 * cap8 + (int)((old >> 32) & 0xFFFFu);
                hbase[s0 + 3] = sb + 3 * cap8 + (int)((old >> 48) & 0xFFFFu);
            }
            hcnt[s0] = 0; hcnt[s0 + 1] = 0; hcnt[s0 + 2] = 0; hcnt[s0 + 3] = 0;
        }
    }
    __syncthreads();

    #pragma unroll
    for (int k = 0; k < 14; ++k) {
        if (dv[k] != 0xFFFFFFFFu) {
            unsigned d = dv[k];
            int sub = (int)(d >> 5);
            int p = hbase[sub] + atomicAdd(&hcnt[sub], 1);
            int end = (sub >> 3) * cap + ((sub & 7) + 1) * cap8;
            if (p < end)
                binned[p] = (((unsigned)sv[k]) << 8) | (d & 255u);
        }
    }
}

// L2-resident quarter gather. One block per (32-node sub-bucket, quarter).
__launch_bounds__(256)
__global__ void gather_q(const unsigned short* __restrict__ xq,
                         const unsigned int* __restrict__ binned,
                         const unsigned long long* __restrict__ gfill,
                         float* __restrict__ outf,
                         int N, int nsub, int cap8, int ssh) {
    __shared__ int scnt[32];
    __shared__ int sbase[32];
    __shared__ int sfill[32];
    __shared__ int sortbuf[SORT_CAP];

    int i = blockIdx.x;
    int q = (i & 7) >> 1;                // quarter pinned to XCD pair
    int s = ((i >> 3) << 1) | (i & 1);   // sub-bucket
    if (s >= nsub) return;
    int n0 = s << 5;
    if (n0 >= N) return;
    int nn = N - n0; if (nn > 32) nn = 32;

    int t = threadIdx.x;
    int w = t >> 6;
    int lane = t & 63;

    if (t < 32) { scnt[t] = 0; sfill[t] = 0; }
    __syncthreads();

    // ---- reg-staged edge pass ----
    int elo = s * cap8;
    int cnt = (int)((gfill[s >> 2] >> (16 * (s & 3))) & 0xFFFFull);
    if (cnt > cap8) cnt = cap8;
    int ehi = elo + cnt;

    unsigned ev[EVMAX];
    #pragma unroll
    for (int k = 0; k < EVMAX; ++k) {
        int idx = elo + t + k * 256;
        ev[k] = (idx < ehi) ? binned[idx] : 0xFFFFFFFFu;
    }
    #pragma unroll
    for (int k = 0; k < EVMAX; ++k)
        if (ev[k] != 0xFFFFFFFFu) atomicAdd(&scnt[ev[k] & 31], 1);
    __syncthreads();

    // ---- padded (x8) exclusive scan (wave 0) ----
    if (w == 0) {
        int c = (lane < 32) ? scnt[lane] : 0;
        int pc = (c + 7) & ~7;
        int v = pc;
        #pragma unroll
        for (int o = 1; o < 32; o <<= 1) {
            int u = __shfl_up(v, o);
            if (lane >= o) v += u;
        }
        if (lane < 32) sbase[lane] = v - pc;
    }
    __syncthreads();

    // ---- place edges + dummy-fill pad slots (disjoint ranges) ----
    #pragma unroll
    for (int k = 0; k < EVMAX; ++k) {
        if (ev[k] != 0xFFFFFFFFu) {
            int d = (int)(ev[k] & 31u);
            int p = sbase[d] + atomicAdd(&sfill[d], 1);
            sortbuf[p] = (int)(ev[k] >> 8);
        }
    }
    if (t < 32) {
        int deg = scnt[t], pc = (deg + 7) & ~7, b0 = sbase[t];
        for (int z = deg; z < pc; ++z) sortbuf[b0 + z] = N;   // zero row
    }
    __syncthreads();

    // ---- gather: wave w handles nodes w*8 .. w*8+7; 8 edges/instr ----
    const unsigned short* slab = xq + (size_t)q * ssh;
    int e = lane >> 3;                   // edge slot 0..7
    int j = lane & 7;                    // dword (2 feats) 0..7
    for (int m = 0; m < 8; ++m) {
        int d = w * 8 + m;
        if (d >= nn) break;
        int deg = scnt[d];
        int s0 = sbase[d];
        int pcd = (deg + 7) & ~7;

        float ax0 = 0.f, ay0 = 0.f, ax1 = 0.f, ay1 = 0.f;
        float ax2 = 0.f, ay2 = 0.f, ax3 = 0.f, ay3 = 0.f;
        int o = 0;
        for (; o + 32 <= pcd; o += 32) {
            int i0 = sortbuf[s0 + o + e];
            int i1 = sortbuf[s0 + o + 8 + e];
            int i2 = sortbuf[s0 + o + 16 + e];
            int i3 = sortbuf[s0 + o + 24 + e];
            unsigned v0 = *(const unsigned*)(slab + (size_t)i0 * 16 + j * 2);
            unsigned v1 = *(const unsigned*)(slab + (size_t)i1 * 16 + j * 2);
            unsigned v2 = *(const unsigned*)(slab + (size_t)i2 * 16 + j * 2);
            unsigned v3 = *(const unsigned*)(slab + (size_t)i3 * 16 + j * 2);
            ax0 += bf2f_lo(v0); ay0 += bf2f_hi(v0);
            ax1 += bf2f_lo(v1); ay1 += bf2f_hi(v1);
            ax2 += bf2f_lo(v2); ay2 += bf2f_hi(v2);
            ax3 += bf2f_lo(v3); ay3 += bf2f_hi(v3);
        }
        for (; o < pcd; o += 8) {
            int id = sortbuf[s0 + o + e];
            unsigned v = *(const unsigned*)(slab + (size_t)id * 16 + j * 2);
            ax0 += bf2f_lo(v); ay0 += bf2f_hi(v);
        }

        float sx = (ax0 + ax1) + (ax2 + ax3);
        float sy = (ay0 + ay1) + (ay2 + ay3);
        sx += __shfl_xor(sx, 8); sx += __shfl_xor(sx, 16); sx += __shfl_xor(sx, 32);
        sy += __shfl_xor(sy, 8); sy += __shfl_xor(sy, 16); sy += __shfl_xor(sy, 32);

        if (lane < 8) {
            float inv = 1.0f / fmaxf((float)deg, 1.0f);
            float2 mv; mv.x = sx * inv; mv.y = sy * inv;
            *(float2*)&outf[(size_t)(n0 + d) * DFEAT + q * 16 + j * 2] = mv;
        }
    }
}

// Dual-GEMM epilogue: reads f32 means from out, overwrites out.
__launch_bounds__(256)
__global__ void sage_gemm(const unsigned short* __restrict__ xq,
                          const unsigned short* __restrict__ wl16,
                          const unsigned short* __restrict__ wr16,
                          const float* __restrict__ bl,
                          float* __restrict__ outf,
                          int N, int ssh) {
    int n0 = blockIdx.x << 6;
    if (n0 >= N) return;
    int t = threadIdx.x;
    int w = t >> 6;
    int lane = t & 63;
    int nt = w;
    int n15 = lane & 15;
    int quad = lane >> 4;

    bf16x8 bfrag[4];
    #pragma unroll
    for (int kk = 0; kk < 4; ++kk) {
        const unsigned short* W = (kk < 2) ? wl16 : wr16;
        int kbase = (kk & 1) * 32 + quad * 8;
        #pragma unroll
        for (int jj = 0; jj < 8; ++jj)
            bfrag[kk][jj] = (short)W[(kbase + jj) * DFEAT + nt * 16 + n15];
    }
    float bias = bl[nt * 16 + n15];

    // phase 1: stage all means fragments (reads of out) into registers
    bf16x8 am[4][2];
    #pragma unroll
    for (int tt = 0; tt < 4; ++tt) {
        int m = tt * 16 + n15;
        int grow = n0 + m; if (grow >= N) grow = N - 1;
        #pragma unroll
        for (int kk2 = 0; kk2 < 2; ++kk2) {
            const float* mp = outf + (size_t)grow * DFEAT + kk2 * 32 + quad * 8;
            bf16x8 fr;
            #pragma unroll
            for (int jj = 0; jj < 8; ++jj)
                fr[jj] = (short)f2bf(mp[jj]);
            am[tt][kk2] = fr;
        }
    }
    __syncthreads();   // all means reads complete before any final write

    // phase 2: MFMA + overwrite out
    #pragma unroll
    for (int tt = 0; tt < 4; ++tt) {
        int m = tt * 16 + n15;
        int grow = n0 + m; if (grow >= N) grow = N - 1;

        const unsigned short* p2 = xq + (size_t)(quad >> 1) * ssh
                                 + (size_t)grow * 16 + (quad & 1) * 8;
        const unsigned short* p3 = xq + (size_t)(2 + (quad >> 1)) * ssh
                                 + (size_t)grow * 16 + (quad & 1) * 8;
        bf16x8 a2 = *(const bf16x8*)p2;
        bf16x8 a3 = *(const bf16x8*)p3;

        f32x4 c = {0.f, 0.f, 0.f, 0.f};
        c = __builtin_amdgcn_mfma_f32_16x16x32_bf16(am[tt][0], bfrag[0], c, 0, 0, 0);
        c = __builtin_amdgcn_mfma_f32_16x16x32_bf16(am[tt][1], bfrag[1], c, 0, 0, 0);
        c = __builtin_amdgcn_mfma_f32_16x16x32_bf16(a2, bfrag[2], c, 0, 0, 0);
        c = __builtin_amdgcn_mfma_f32_16x16x32_bf16(a3, bfrag[3], c, 0, 0, 0);

        #pragma unroll
        for (int r = 0; r < 4; ++r) {
            int orow = n0 + tt * 16 + quad * 4 + r;
            if (orow < N)
                outf[(size_t)orow * DFEAT + nt * 16 + n15] = c[r] + bias;
        }
    }
}

extern "C" void kernel_launch(void* const* d_in, const int* in_sizes, int n_in,
                              void* d_out, int out_size, void* d_ws, size_t ws_size,
                              hipStream_t stream) {
    const float* x  = (const float*)d_in[0];
    const int*   ei = (const int*)d_in[1];     // [2,E] flat: src then dst
    const float* Wl = (const float*)d_in[2];
    const float* bl = (const float*)d_in[3];
    const float* Wr = (const float*)d_in[4];
    float* out = (float*)d_out;

    const int N = in_sizes[0] / DFEAT;         // 100000
    const int E = in_sizes[1] / 2;             // 1600000
    const int* src = ei;
    const int* dst = ei + E;

    const int nbuck = (N + 255) >> 8;          // 391 coarse buckets
    const int nsub  = nbuck * 8;               // 3128 32-node sub-buckets
    const int ssh   = (N + 8) * 16;            // shorts per quarter slab

    // Sub-region capacity: target mean+11sigma (768), shrink only if tight.
    size_t fixedBytes = 2 * MAXBUCK * sizeof(unsigned long long)
                      + 2 * DFEAT * DFEAT * sizeof(short)
                      + (size_t)4 * ssh * sizeof(short) + 4096;
    size_t avail = (ws_size > fixedBytes) ? (ws_size - fixedBytes) : 0;
    long long c8 = (long long)(avail / ((size_t)nsub * sizeof(int)));
    int cap8 = (c8 > 768) ? 768 : (int)c8;
    cap8 &= ~63;
    if (cap8 < 64) cap8 = 64;                  // degenerate-ws guard
    int cap = cap8 * 8;

    // ws: [gfill u64*1024][binned nbuck*cap][wl16][wr16][xq 4 slabs]
    unsigned long long* gfill = (unsigned long long*)d_ws;
    unsigned int* binned = (unsigned int*)(gfill + 2 * MAXBUCK);
    unsigned short* wl16 = (unsigned short*)(binned + (size_t)nbuck * cap);
    unsigned short* wr16 = wl16 + DFEAT * DFEAT;
    unsigned short* xq   = wr16 + DFEAT * DFEAT;

    hipMemsetAsync(gfill, 0, 2 * MAXBUCK * sizeof(unsigned long long), stream);

    int nx4 = N * DFEAT / 4;
    int nbin = (E + BCHUNK - 1) / BCHUNK;      // 224
    prep_bin<<<CONVB + nbin, 512, 0, stream>>>(
        x, Wl, Wr, src, dst, xq, wl16, wr16, gfill, binned,
        nx4, E, nbuck, cap, cap8, ssh, N);

    int MA = (nsub + 1) >> 1;                  // 1564
    gather_q<<<8 * MA, 256, 0, stream>>>(
        xq, binned, gfill, out, N, nsub, cap8, ssh);

    sage_gemm<<<(N + 63) >> 6, 256, 0, stream>>>(
        xq, wl16, wr16, bl, out, N, ssh);
}

// Round 9
// 167.791 us; speedup vs baseline: 1.2338x; 1.2338x over previous
//
#include <hip/hip_runtime.h>

// GraphSAGEConv: out_i = mean_{j in N(i)} x_j @ W_l + b_l + x_i @ W_r
// N=100000, E=1600000, D_in=D_out=64.
//
// REVERT: verbatim restore of the round-6 configuration (measured 165.2 us,
// best of session).  Round-7 (more blocks) and round-8 (L2 quarter-slab
// pinning) both fired their falsifiers: the gather is in a mixed
// fabric/issue regime (~59 us) that resists concurrency, grain, and
// locality levers.  Bank the best.
//
// 3 dispatches:
//   memset:   gfill[512] u64 = 0 (4 KB)
//   prep_bin: heterogeneous single dispatch, 512 thr/block:
//             - blocks [0,192): convert x->bf16 xh, Wl/Wr->bf16 (grid-strided)
//             - blocks [192, +447): binning, 3584 edges each, reg-staged
//               single read of dst/src (7 edges/thread):
//                 LDS hist at 64-node sub-bucket granularity (1564 counters)
//                 -> PACKED u64 reservation: one atomicAdd reserves all 4
//                    sub-regions of a coarse bucket (4x16-bit fields;
//                    per-sub totals ~1024 << 65536, no cross-field carry)
//                 -> scatter packed (src<<8)|(dst&255) into
//                    binned[cb*cap + q*cap4 + off], sub-region-end guarded
//             convert stream hides under the atomic/scatter-bound binning.
//   sage_fused: one 256-thr block per 64 nodes, reads EXACTLY its own
//             sub-region:
//             - blockIdx swizzled so the 4 quarters of a bucket share
//               blockIdx%8 (same XCD -> shared L2 for xh reuse)
//             - single reg-staged pass: <=6 edges/thread -> LDS hist ->
//               wave-0 shfl scan -> place into sortbuf (binned read ONCE)
//             - per-wave aggregation: 16 nodes/wave; per-edge index via
//               uniform-address LDS broadcast read; half-wave ushort2
//               gathers of 128B bf16 rows, 8-deep ILP, f32 accumulate
//             - means bf16 in LDS (72-short pitch, bank-safe)
//             - dual-GEMM via mfma_f32_16x16x32_bf16 (K=128 fused)

#define DFEAT 64
#define MAXBUCK 512                  // coarse buckets (256 nodes), N <= 131072
#define NSUB (MAXBUCK * 4)           // 64-node sub-buckets
#define SORT_CAP 2048                // LDS edge capacity per 64-node block
#define MLD 72                       // means row pitch in shorts (bank-safe)
#define EVMAX 6                      // cap4/256 = 1536/256 reg-stage depth
#define CONVB 192                    // convert blocks
#define BCHUNK 3584                  // edges per binning block (7 * 512)

typedef short bf16x8 __attribute__((ext_vector_type(8)));
typedef float f32x4 __attribute__((ext_vector_type(4)));

static __device__ __forceinline__ unsigned short f2bf(float f) {
    unsigned int u = __float_as_uint(f);
    unsigned int r = (u + 0x7FFFu + ((u >> 16) & 1u)) >> 16;   // RNE
    return (unsigned short)r;
}
static __device__ __forceinline__ float bf2f_lo(unsigned int u) {
    return __uint_as_float(u << 16);
}
static __device__ __forceinline__ float bf2f_hi(unsigned int u) {
    return __uint_as_float(u & 0xFFFF0000u);
}

// heterogeneous: convert blocks + binning blocks, one dispatch.
__launch_bounds__(512)
__global__ void prep_bin(const float* __restrict__ x,
                         const float* __restrict__ Wl,
                         const float* __restrict__ Wr,
                         const int* __restrict__ src,
                         const int* __restrict__ dst,
                         unsigned short* __restrict__ xh,
                         unsigned short* __restrict__ wl16,
                         unsigned short* __restrict__ wr16,
                         unsigned long long* __restrict__ gfill,
                         unsigned int* __restrict__ binned,
                         int nx4, int E, int nbuck, int cap, int cap4) {
    __shared__ int hcnt[NSUB];
    __shared__ int hbase[NSUB];
    int b = blockIdx.x, t = threadIdx.x;

    // ---- convert blocks ----
    if (b < CONVB) {
        int total = 2048 + nx4;
        for (int i = b * 512 + t; i < total; i += CONVB * 512) {
            const float* sp; unsigned short* dp; int k;
            if (i < 1024)      { sp = Wl; dp = wl16; k = i; }
            else if (i < 2048) { sp = Wr; dp = wr16; k = i - 1024; }
            else               { sp = x;  dp = xh;   k = i - 2048; }
            float4 v = ((const float4*)sp)[k];
            ushort4 hh;
            hh.x = f2bf(v.x); hh.y = f2bf(v.y); hh.z = f2bf(v.z); hh.w = f2bf(v.w);
            ((ushort4*)dp)[k] = hh;
        }
        return;
    }

    // ---- binning blocks ----
    int bb = b - CONVB;
    int lo = bb * BCHUNK;
    int hi = lo + BCHUNK; if (hi > E) hi = E;

    for (int i = t; i < NSUB; i += 512) hcnt[i] = 0;

    // reg-stage this block's edges (dst + src), read once
    unsigned dv[7]; int sv[7];
    #pragma unroll
    for (int k = 0; k < 7; ++k) {
        int i = lo + t + (k << 9);
        bool ok = (i < hi);
        dv[k] = ok ? (unsigned)dst[i] : 0xFFFFFFFFu;
        sv[k] = ok ? src[i] : 0;
    }
    __syncthreads();

    // LDS histogram at sub-bucket granularity
    #pragma unroll
    for (int k = 0; k < 7; ++k)
        if (dv[k] != 0xFFFFFFFFu) atomicAdd(&hcnt[dv[k] >> 6], 1);
    __syncthreads();

    // packed u64 reservation: one atomic per coarse bucket per block
    for (int i = t; i < nbuck; i += 512) {
        int c0 = hcnt[4 * i], c1 = hcnt[4 * i + 1];
        int c2 = hcnt[4 * i + 2], c3 = hcnt[4 * i + 3];
        unsigned long long add =  (unsigned long long)(unsigned)c0
                               | ((unsigned long long)(unsigned)c1 << 16)
                               | ((unsigned long long)(unsigned)c2 << 32)
                               | ((unsigned long long)(unsigned)c3 << 48);
        int base = i * cap;
        if (add) {
            unsigned long long old = atomicAdd(&gfill[i], add);
            hbase[4 * i + 0] = base            + (int)( old        & 0xFFFFu);
            hbase[4 * i + 1] = base +     cap4 + (int)((old >> 16) & 0xFFFFu);
            hbase[4 * i + 2] = base + 2 * cap4 + (int)((old >> 32) & 0xFFFFu);
            hbase[4 * i + 3] = base + 3 * cap4 + (int)((old >> 48) & 0xFFFFu);
        }
        hcnt[4 * i] = 0; hcnt[4 * i + 1] = 0;
        hcnt[4 * i + 2] = 0; hcnt[4 * i + 3] = 0;
    }
    __syncthreads();

    // scatter from registers (sub-region-end guarded)
    #pragma unroll
    for (int k = 0; k < 7; ++k) {
        if (dv[k] != 0xFFFFFFFFu) {
            unsigned d = dv[k];
            int sub = (int)(d >> 6);
            int p = hbase[sub] + atomicAdd(&hcnt[sub], 1);
            int end = (sub >> 2) * cap + ((sub & 3) + 1) * cap4;
            if (p < end)
                binned[p] = (((unsigned)sv[k]) << 8) | (d & 255u);
        }
    }
}

// Fused fine-sort + aggregate + dual-GEMM. One block per 64 nodes.
__launch_bounds__(256)
__global__ void sage_fused(const unsigned short* __restrict__ xh,
                           const unsigned int* __restrict__ binned,
                           const unsigned long long* __restrict__ gfill,
                           const unsigned short* __restrict__ wl16,
                           const unsigned short* __restrict__ wr16,
                           const float* __restrict__ bl,
                           float* __restrict__ out,
                           int N, int nbuck, int cap, int cap4) {
    __shared__ int scnt[64];
    __shared__ int sbase[64];
    __shared__ int sfill[64];
    __shared__ int sortbuf[SORT_CAP];
    __shared__ unsigned short means[64 * MLD];   // 9216 B

    int xx = blockIdx.x & 7;
    int kq = blockIdx.x >> 3;
    int cb = xx + ((kq >> 2) << 3);     // coarse bucket (XCD-shared quarters)
    int q  = kq & 3;                    // 64-node quarter
    if (cb >= nbuck) return;
    int n0 = (cb << 8) + (q << 6);
    if (n0 >= N) return;
    int nn = N - n0; if (nn > 64) nn = 64;

    int t = threadIdx.x;
    int w = t >> 6;
    int lane = t & 63;

    if (t < 64) { scnt[t] = 0; sfill[t] = 0; }
    __syncthreads();

    // ---- single reg-staged pass over OUR sub-region ----
    int elo = cb * cap + q * cap4;
    int cnt = (int)((gfill[cb] >> (16 * q)) & 0xFFFFull);
    if (cnt > cap4) cnt = cap4;
    int ehi = elo + cnt;

    unsigned int ev[EVMAX];
    #pragma unroll
    for (int k = 0; k < EVMAX; ++k) {
        int i = elo + t + k * 256;
        ev[k] = (i < ehi) ? binned[i] : 0xFFFFFFFFu;   // packed < 2^25, safe
    }
    #pragma unroll
    for (int k = 0; k < EVMAX; ++k)
        if (ev[k] != 0xFFFFFFFFu) atomicAdd(&scnt[ev[k] & 63], 1);
    __syncthreads();

    // ---- exclusive scan of 64 counters (wave 0, shfl) ----
    if (w == 0) {
        int c = scnt[lane];
        int v = c;
        #pragma unroll
        for (int o = 1; o < 64; o <<= 1) {
            int u = __shfl_up(v, o);
            if (lane >= o) v += u;
        }
        sbase[lane] = v - c;
    }
    __syncthreads();

    // ---- place edges into LDS (from registers) ----
    #pragma unroll
    for (int k = 0; k < EVMAX; ++k) {
        if (ev[k] != 0xFFFFFFFFu) {
            int d = (int)(ev[k] & 63u);
            int p = sbase[d] + atomicAdd(&sfill[d], 1);
            if (p < SORT_CAP) sortbuf[p] = (int)(ev[k] >> 8);
        }
    }
    __syncthreads();

    // ---- aggregation: wave w handles nodes w*16 .. w*16+15 ----
    int half = lane >> 5;
    int l2 = lane & 31;
    for (int m = 0; m < 16; ++m) {
        int d = w * 16 + m;
        if (d >= nn) break;
        int s0 = sbase[d];
        int deg = scnt[d];
        int s1 = s0 + deg; if (s1 > SORT_CAP) s1 = SORT_CAP;

        float2 acc[8];
        #pragma unroll
        for (int u = 0; u < 8; ++u) { acc[u].x = 0.f; acc[u].y = 0.f; }

        for (int base = s0; base < s1; base += 64) {
            int cc = s1 - base; if (cc > 64) cc = 64;
            int pairs = cc >> 1;
            int s = 0;
            for (; s + 8 <= pairs; s += 8) {
                unsigned int vv[8];
                #pragma unroll
                for (int u = 0; u < 8; ++u) {
                    int id = sortbuf[base + 2 * (s + u) + half];  // LDS broadcast
                    vv[u] = *(const unsigned int*)(xh + (size_t)id * DFEAT + l2 * 2);
                }
                #pragma unroll
                for (int u = 0; u < 8; ++u) {
                    acc[u].x += bf2f_lo(vv[u]);
                    acc[u].y += bf2f_hi(vv[u]);
                }
            }
            for (; s < pairs; ++s) {
                int id = sortbuf[base + 2 * s + half];
                unsigned int v = *(const unsigned int*)(xh + (size_t)id * DFEAT + l2 * 2);
                acc[0].x += bf2f_lo(v);
                acc[0].y += bf2f_hi(v);
            }
            if (cc & 1) {
                int id = sortbuf[base + cc - 1];
                unsigned int v = *(const unsigned int*)(xh + (size_t)id * DFEAT + l2 * 2);
                if (half == 0) {
                    acc[1].x += bf2f_lo(v);
                    acc[1].y += bf2f_hi(v);
                }
            }
        }

        float2 s2;
        s2.x = ((acc[0].x + acc[1].x) + (acc[2].x + acc[3].x))
             + ((acc[4].x + acc[5].x) + (acc[6].x + acc[7].x));
        s2.y = ((acc[0].y + acc[1].y) + (acc[2].y + acc[3].y))
             + ((acc[4].y + acc[5].y) + (acc[6].y + acc[7].y));
        s2.x += __shfl_xor(s2.x, 32);
        s2.y += __shfl_xor(s2.y, 32);

        if (lane < 32) {
            float inv = 1.0f / fmaxf((float)deg, 1.0f);
            unsigned int pk = (unsigned int)f2bf(s2.x * inv)
                            | ((unsigned int)f2bf(s2.y * inv) << 16);
            *(unsigned int*)&means[d * MLD + l2 * 2] = pk;
        }
    }
    __syncthreads();

    // ---- GEMM: wave w = column quadrant; 4 row-tiles x 4 k-chunks ----
    int nt = w;
    int n15 = lane & 15;
    int quad = lane >> 4;

    bf16x8 bfrag[4];
    #pragma unroll
    for (int kk = 0; kk < 4; ++kk) {
        const unsigned short* W = (kk < 2) ? wl16 : wr16;
        int kbase = (kk & 1) * 32 + quad * 8;
        #pragma unroll
        for (int j = 0; j < 8; ++j)
            bfrag[kk][j] = (short)W[(kbase + j) * DFEAT + nt * 16 + n15];
    }
    float bias = bl[nt * 16 + n15];

    #pragma unroll
    for (int tt = 0; tt < 4; ++tt) {
        int m = tt * 16 + n15;                       // local node row (A row)
        int grow = n0 + m; if (grow >= N) grow = N - 1;

        bf16x8 a0 = *(const bf16x8*)&means[m * MLD + quad * 8];
        bf16x8 a1 = *(const bf16x8*)&means[m * MLD + 32 + quad * 8];
        bf16x8 a2 = *(const bf16x8*)(xh + (size_t)grow * DFEAT + quad * 8);
        bf16x8 a3 = *(const bf16x8*)(xh + (size_t)grow * DFEAT + 32 + quad * 8);

        f32x4 c = {0.f, 0.f, 0.f, 0.f};
        c = __builtin_amdgcn_mfma_f32_16x16x32_bf16(a0, bfrag[0], c, 0, 0, 0);
        c = __builtin_amdgcn_mfma_f32_16x16x32_bf16(a1, bfrag[1], c, 0, 0, 0);
        c = __builtin_amdgcn_mfma_f32_16x16x32_bf16(a2, bfrag[2], c, 0, 0, 0);
        c = __builtin_amdgcn_mfma_f32_16x16x32_bf16(a3, bfrag[3], c, 0, 0, 0);

        #pragma unroll
        for (int r = 0; r < 4; ++r) {
            int orow = n0 + tt * 16 + quad * 4 + r;
            if (orow < N)
                out[(size_t)orow * DFEAT + nt * 16 + n15] = c[r] + bias;
        }
    }
}

extern "C" void kernel_launch(void* const* d_in, const int* in_sizes, int n_in,
                              void* d_out, int out_size, void* d_ws, size_t ws_size,
                              hipStream_t stream) {
    const float* x  = (const float*)d_in[0];
    const int*   ei = (const int*)d_in[1];     // [2,E] flat: src then dst
    const float* Wl = (const float*)d_in[2];
    const float* bl = (const float*)d_in[3];
    const float* Wr = (const float*)d_in[4];
    float* out = (float*)d_out;

    const int N = in_sizes[0] / DFEAT;         // 100000
    const int E = in_sizes[1] / 2;             // 1600000
    const int* src = ei;
    const int* dst = ei + E;

    const int nbuck = (N + 255) >> 8;          // 391 coarse buckets
    const int nsub  = nbuck * 4;               // 1564 sub-buckets

    // Sub-region capacity: target mean+16sigma (1536), shrink only if ws is
    // tight.  cap4 is 64-aligned so every sub-region is 256B-aligned.
    size_t fixedBytes = MAXBUCK * sizeof(unsigned long long)
                      + 2 * DFEAT * DFEAT * sizeof(short)
                      + (size_t)N * DFEAT * sizeof(short) + 4096;
    size_t avail = (ws_size > fixedBytes) ? (ws_size - fixedBytes) : 0;
    long long c4 = (long long)(avail / ((size_t)nsub * sizeof(int)));
    int cap4 = (c4 > 1536) ? 1536 : (int)c4;
    cap4 &= ~63;
    if (cap4 < 64) cap4 = 64;                  // degenerate-ws guard (no OOB)
    int cap = cap4 * 4;

    // ws: [gfill u64*512][binned nbuck*cap][wl16 4096][wr16 4096][xh N*64]
    unsigned long long* gfill = (unsigned long long*)d_ws;
    unsigned int* binned = (unsigned int*)(gfill + MAXBUCK);
    unsigned short* wl16 = (unsigned short*)(binned + (size_t)nbuck * cap);
    unsigned short* wr16 = wl16 + DFEAT * DFEAT;
    unsigned short* xh   = wr16 + DFEAT * DFEAT;

    hipMemsetAsync(gfill, 0, MAXBUCK * sizeof(unsigned long long), stream);

    int nx4 = N * DFEAT / 4;
    int nbin = (E + BCHUNK - 1) / BCHUNK;      // 447
    prep_bin<<<CONVB + nbin, 512, 0, stream>>>(
        x, Wl, Wr, src, dst, xh, wl16, wr16, gfill, binned,
        nx4, E, nbuck, cap, cap4);

    int mg = (nbuck + 7) >> 3;
    sage_fused<<<mg * 32, 256, 0, stream>>>(
        xh, binned, gfill, wl16, wr16, bl, out, N, nbuck, cap, cap4);
}

// Round 10
// 167.042 us; speedup vs baseline: 1.2393x; 1.0045x over previous
//
#include <hip/hip_runtime.h>

// GraphSAGEConv: out_i = mean_{j in N(i)} x_j @ W_l + b_l + x_i @ W_r
// N=100000, E=1600000, D_in=D_out=64.
//
// Round-10: banked r6/r9 config with ONE change — prep_bin's binning chunk
// grows 4x (BCHUNK 3584 -> 14336, 28 edges/thread, dst-only reg-staging).
// Longer per-(block,sub) scatter runs (2.3 -> 9.2 edges) cut the scattered
// write RMW line traffic ~4x (~70 MB -> ~18 MB) and reservation atomics 4x.
// sage_fused is byte-identical to the measured-best round-9 kernel.
//
// 3 dispatches:
//   memset:   gfill[512] u64 = 0 (4 KB)
//   prep_bin: heterogeneous single dispatch, 512 thr/block:
//             - blocks [0,192): convert x->bf16 xh, Wl/Wr->bf16 (grid-strided)
//             - blocks [192, +112): binning, 14336 edges each, dst reg-staged
//               (28 edges/thread; src streamed fresh in the scatter phase):
//                 LDS hist at 64-node sub-bucket granularity (1564 counters)
//                 -> PACKED u64 reservation: one atomicAdd reserves all 4
//                    sub-regions of a coarse bucket (4x16-bit fields;
//                    per-sub totals ~1024 << 65536, no cross-field carry)
//                 -> scatter packed (src<<8)|(dst&255) into
//                    binned[cb*cap + q*cap4 + off], sub-region-end guarded
//   sage_fused: one 256-thr block per 64 nodes, reads EXACTLY its own
//             sub-region (r6-proven):
//             - blockIdx swizzled so the 4 quarters of a bucket share
//               blockIdx%8 (same XCD -> shared L2 for xh reuse)
//             - single reg-staged pass: <=6 edges/thread -> LDS hist ->
//               wave-0 shfl scan -> place into sortbuf (binned read ONCE)
//             - per-wave aggregation: 16 nodes/wave; per-edge index via
//               uniform-address LDS broadcast read; half-wave ushort2
//               gathers of 128B bf16 rows, 8-deep ILP, f32 accumulate
//             - means bf16 in LDS (72-short pitch, bank-safe)
//             - dual-GEMM via mfma_f32_16x16x32_bf16 (K=128 fused)

#define DFEAT 64
#define MAXBUCK 512                  // coarse buckets (256 nodes), N <= 131072
#define NSUB (MAXBUCK * 4)           // 64-node sub-buckets
#define SORT_CAP 2048                // LDS edge capacity per 64-node block
#define MLD 72                       // means row pitch in shorts (bank-safe)
#define EVMAX 6                      // cap4/256 = 1536/256 reg-stage depth
#define CONVB 192                    // convert blocks
#define EPT 28                       // binning edges per thread (dst staged)
#define BCHUNK (EPT * 512)           // 14336 edges per binning block

typedef short bf16x8 __attribute__((ext_vector_type(8)));
typedef float f32x4 __attribute__((ext_vector_type(4)));

static __device__ __forceinline__ unsigned short f2bf(float f) {
    unsigned int u = __float_as_uint(f);
    unsigned int r = (u + 0x7FFFu + ((u >> 16) & 1u)) >> 16;   // RNE
    return (unsigned short)r;
}
static __device__ __forceinline__ float bf2f_lo(unsigned int u) {
    return __uint_as_float(u << 16);
}
static __device__ __forceinline__ float bf2f_hi(unsigned int u) {
    return __uint_as_float(u & 0xFFFF0000u);
}

// heterogeneous: convert blocks + binning blocks, one dispatch.
__launch_bounds__(512)
__global__ void prep_bin(const float* __restrict__ x,
                         const float* __restrict__ Wl,
                         const float* __restrict__ Wr,
                         const int* __restrict__ src,
                         const int* __restrict__ dst,
                         unsigned short* __restrict__ xh,
                         unsigned short* __restrict__ wl16,
                         unsigned short* __restrict__ wr16,
                         unsigned long long* __restrict__ gfill,
                         unsigned int* __restrict__ binned,
                         int nx4, int E, int nbuck, int cap, int cap4) {
    __shared__ int hcnt[NSUB];
    __shared__ int hbase[NSUB];
    int b = blockIdx.x, t = threadIdx.x;

    // ---- convert blocks ----
    if (b < CONVB) {
        int total = 2048 + nx4;
        for (int i = b * 512 + t; i < total; i += CONVB * 512) {
            const float* sp; unsigned short* dp; int k;
            if (i < 1024)      { sp = Wl; dp = wl16; k = i; }
            else if (i < 2048) { sp = Wr; dp = wr16; k = i - 1024; }
            else               { sp = x;  dp = xh;   k = i - 2048; }
            float4 v = ((const float4*)sp)[k];
            ushort4 hh;
            hh.x = f2bf(v.x); hh.y = f2bf(v.y); hh.z = f2bf(v.z); hh.w = f2bf(v.w);
            ((ushort4*)dp)[k] = hh;
        }
        return;
    }

    // ---- binning blocks ----
    int bb = b - CONVB;
    int lo = bb * BCHUNK;
    int hi = lo + BCHUNK; if (hi > E) hi = E;

    for (int i = t; i < NSUB; i += 512) hcnt[i] = 0;

    // reg-stage this block's dst values (read once; src streamed later)
    unsigned dv[EPT];
    #pragma unroll
    for (int k = 0; k < EPT; ++k) {
        int i = lo + t + (k << 9);
        dv[k] = (i < hi) ? (unsigned)dst[i] : 0xFFFFFFFFu;
    }
    __syncthreads();

    // LDS histogram at sub-bucket granularity
    #pragma unroll
    for (int k = 0; k < EPT; ++k)
        if (dv[k] != 0xFFFFFFFFu) atomicAdd(&hcnt[dv[k] >> 6], 1);
    __syncthreads();

    // packed u64 reservation: one atomic per coarse bucket per block
    for (int i = t; i < nbuck; i += 512) {
        int c0 = hcnt[4 * i], c1 = hcnt[4 * i + 1];
        int c2 = hcnt[4 * i + 2], c3 = hcnt[4 * i + 3];
        unsigned long long add =  (unsigned long long)(unsigned)c0
                               | ((unsigned long long)(unsigned)c1 << 16)
                               | ((unsigned long long)(unsigned)c2 << 32)
                               | ((unsigned long long)(unsigned)c3 << 48);
        int base = i * cap;
        if (add) {
            unsigned long long old = atomicAdd(&gfill[i], add);
            hbase[4 * i + 0] = base            + (int)( old        & 0xFFFFu);
            hbase[4 * i + 1] = base +     cap4 + (int)((old >> 16) & 0xFFFFu);
            hbase[4 * i + 2] = base + 2 * cap4 + (int)((old >> 32) & 0xFFFFu);
            hbase[4 * i + 3] = base + 3 * cap4 + (int)((old >> 48) & 0xFFFFu);
        }
        hcnt[4 * i] = 0; hcnt[4 * i + 1] = 0;
        hcnt[4 * i + 2] = 0; hcnt[4 * i + 3] = 0;
    }
    __syncthreads();

    // scatter: dst from registers, src streamed (first touch, coalesced)
    #pragma unroll
    for (int k = 0; k < EPT; ++k) {
        if (dv[k] != 0xFFFFFFFFu) {
            unsigned d = dv[k];
            int i = lo + t + (k << 9);
            unsigned sx = (unsigned)src[i];
            int sub = (int)(d >> 6);
            int p = hbase[sub] + atomicAdd(&hcnt[sub], 1);
            int end = (sub >> 2) * cap + ((sub & 3) + 1) * cap4;
            if (p < end)
                binned[p] = (sx << 8) | (d & 255u);
        }
    }
}

// Fused fine-sort + aggregate + dual-GEMM. One block per 64 nodes.
__launch_bounds__(256)
__global__ void sage_fused(const unsigned short* __restrict__ xh,
                           const unsigned int* __restrict__ binned,
                           const unsigned long long* __restrict__ gfill,
                           const unsigned short* __restrict__ wl16,
                           const unsigned short* __restrict__ wr16,
                           const float* __restrict__ bl,
                           float* __restrict__ out,
                           int N, int nbuck, int cap, int cap4) {
    __shared__ int scnt[64];
    __shared__ int sbase[64];
    __shared__ int sfill[64];
    __shared__ int sortbuf[SORT_CAP];
    __shared__ unsigned short means[64 * MLD];   // 9216 B

    int xx = blockIdx.x & 7;
    int kq = blockIdx.x >> 3;
    int cb = xx + ((kq >> 2) << 3);     // coarse bucket (XCD-shared quarters)
    int q  = kq & 3;                    // 64-node quarter
    if (cb >= nbuck) return;
    int n0 = (cb << 8) + (q << 6);
    if (n0 >= N) return;
    int nn = N - n0; if (nn > 64) nn = 64;

    int t = threadIdx.x;
    int w = t >> 6;
    int lane = t & 63;

    if (t < 64) { scnt[t] = 0; sfill[t] = 0; }
    __syncthreads();

    // ---- single reg-staged pass over OUR sub-region ----
    int elo = cb * cap + q * cap4;
    int cnt = (int)((gfill[cb] >> (16 * q)) & 0xFFFFull);
    if (cnt > cap4) cnt = cap4;
    int ehi = elo + cnt;

    unsigned int ev[EVMAX];
    #pragma unroll
    for (int k = 0; k < EVMAX; ++k) {
        int i = elo + t + k * 256;
        ev[k] = (i < ehi) ? binned[i] : 0xFFFFFFFFu;   // packed < 2^25, safe
    }
    #pragma unroll
    for (int k = 0; k < EVMAX; ++k)
        if (ev[k] != 0xFFFFFFFFu) atomicAdd(&scnt[ev[k] & 63], 1);
    __syncthreads();

    // ---- exclusive scan of 64 counters (wave 0, shfl) ----
    if (w == 0) {
        int c = scnt[lane];
        int v = c;
        #pragma unroll
        for (int o = 1; o < 64; o <<= 1) {
            int u = __shfl_up(v, o);
            if (lane >= o) v += u;
        }
        sbase[lane] = v - c;
    }
    __syncthreads();

    // ---- place edges into LDS (from registers) ----
    #pragma unroll
    for (int k = 0; k < EVMAX; ++k) {
        if (ev[k] != 0xFFFFFFFFu) {
            int d = (int)(ev[k] & 63u);
            int p = sbase[d] + atomicAdd(&sfill[d], 1);
            if (p < SORT_CAP) sortbuf[p] = (int)(ev[k] >> 8);
        }
    }
    __syncthreads();

    // ---- aggregation: wave w handles nodes w*16 .. w*16+15 ----
    int half = lane >> 5;
    int l2 = lane & 31;
    for (int m = 0; m < 16; ++m) {
        int d = w * 16 + m;
        if (d >= nn) break;
        int s0 = sbase[d];
        int deg = scnt[d];
        int s1 = s0 + deg; if (s1 > SORT_CAP) s1 = SORT_CAP;

        float2 acc[8];
        #pragma unroll
        for (int u = 0; u < 8; ++u) { acc[u].x = 0.f; acc[u].y = 0.f; }

        for (int base = s0; base < s1; base += 64) {
            int cc = s1 - base; if (cc > 64) cc = 64;
            int pairs = cc >> 1;
            int s = 0;
            for (; s + 8 <= pairs; s += 8) {
                unsigned int vv[8];
                #pragma unroll
                for (int u = 0; u < 8; ++u) {
                    int id = sortbuf[base + 2 * (s + u) + half];  // LDS broadcast
                    vv[u] = *(const unsigned int*)(xh + (size_t)id * DFEAT + l2 * 2);
                }
                #pragma unroll
                for (int u = 0; u < 8; ++u) {
                    acc[u].x += bf2f_lo(vv[u]);
                    acc[u].y += bf2f_hi(vv[u]);
                }
            }
            for (; s < pairs; ++s) {
                int id = sortbuf[base + 2 * s + half];
                unsigned int v = *(const unsigned int*)(xh + (size_t)id * DFEAT + l2 * 2);
                acc[0].x += bf2f_lo(v);
                acc[0].y += bf2f_hi(v);
            }
            if (cc & 1) {
                int id = sortbuf[base + cc - 1];
                unsigned int v = *(const unsigned int*)(xh + (size_t)id * DFEAT + l2 * 2);
                if (half == 0) {
                    acc[1].x += bf2f_lo(v);
                    acc[1].y += bf2f_hi(v);
                }
            }
        }

        float2 s2;
        s2.x = ((acc[0].x + acc[1].x) + (acc[2].x + acc[3].x))
             + ((acc[4].x + acc[5].x) + (acc[6].x + acc[7].x));
        s2.y = ((acc[0].y + acc[1].y) + (acc[2].y + acc[3].y))
             + ((acc[4].y + acc[5].y) + (acc[6].y + acc[7].y));
        s2.x += __shfl_xor(s2.x, 32);
        s2.y += __shfl_xor(s2.y, 32);

        if (lane < 32) {
            float inv = 1.0f / fmaxf((float)deg, 1.0f);
            unsigned int pk = (unsigned int)f2bf(s2.x * inv)
                            | ((unsigned int)f2bf(s2.y * inv) << 16);
            *(unsigned int*)&means[d * MLD + l2 * 2] = pk;
        }
    }
    __syncthreads();

    // ---- GEMM: wave w = column quadrant; 4 row-tiles x 4 k-chunks ----
    int nt = w;
    int n15 = lane & 15;
    int quad = lane >> 4;

    bf16x8 bfrag[4];
    #pragma unroll
    for (int kk = 0; kk < 4; ++kk) {
        const unsigned short* W = (kk < 2) ? wl16 : wr16;
        int kbase = (kk & 1) * 32 + quad * 8;
        #pragma unroll
        for (int j = 0; j < 8; ++j)
            bfrag[kk][j] = (short)W[(kbase + j) * DFEAT + nt * 16 + n15];
    }
    float bias = bl[nt * 16 + n15];

    #pragma unroll
    for (int tt = 0; tt < 4; ++tt) {
        int m = tt * 16 + n15;                       // local node row (A row)
        int grow = n0 + m; if (grow >= N) grow = N - 1;

        bf16x8 a0 = *(const bf16x8*)&means[m * MLD + quad * 8];
        bf16x8 a1 = *(const bf16x8*)&means[m * MLD + 32 + quad * 8];
        bf16x8 a2 = *(const bf16x8*)(xh + (size_t)grow * DFEAT + quad * 8);
        bf16x8 a3 = *(const bf16x8*)(xh + (size_t)grow * DFEAT + 32 + quad * 8);

        f32x4 c = {0.f, 0.f, 0.f, 0.f};
        c = __builtin_amdgcn_mfma_f32_16x16x32_bf16(a0, bfrag[0], c, 0, 0, 0);
        c = __builtin_amdgcn_mfma_f32_16x16x32_bf16(a1, bfrag[1], c, 0, 0, 0);
        c = __builtin_amdgcn_mfma_f32_16x16x32_bf16(a2, bfrag[2], c, 0, 0, 0);
        c = __builtin_amdgcn_mfma_f32_16x16x32_bf16(a3, bfrag[3], c, 0, 0, 0);

        #pragma unroll
        for (int r = 0; r < 4; ++r) {
            int orow = n0 + tt * 16 + quad * 4 + r;
            if (orow < N)
                out[(size_t)orow * DFEAT + nt * 16 + n15] = c[r] + bias;
        }
    }
}

extern "C" void kernel_launch(void* const* d_in, const int* in_sizes, int n_in,
                              void* d_out, int out_size, void* d_ws, size_t ws_size,
                              hipStream_t stream) {
    const float* x  = (const float*)d_in[0];
    const int*   ei = (const int*)d_in[1];     // [2,E] flat: src then dst
    const float* Wl = (const float*)d_in[2];
    const float* bl = (const float*)d_in[3];
    const float* Wr = (const float*)d_in[4];
    float* out = (float*)d_out;

    const int N = in_sizes[0] / DFEAT;         // 100000
    const int E = in_sizes[1] / 2;             // 1600000
    const int* src = ei;
    const int* dst = ei + E;

    const int nbuck = (N + 255) >> 8;          // 391 coarse buckets
    const int nsub  = nbuck * 4;               // 1564 sub-buckets

    // Sub-region capacity: target mean+16sigma (1536), shrink only if ws is
    // tight.  cap4 is 64-aligned so every sub-region is 256B-aligned.
    size_t fixedBytes = MAXBUCK * sizeof(unsigned long long)
                      + 2 * DFEAT * DFEAT * sizeof(short)
                      + (size_t)N * DFEAT * sizeof(short) + 4096;
    size_t avail = (ws_size > fixedBytes) ? (ws_size - fixedBytes) : 0;
    long long c4 = (long long)(avail / ((size_t)nsub * sizeof(int)));
    int cap4 = (c4 > 1536) ? 1536 : (int)c4;
    cap4 &= ~63;
    if (cap4 < 64) cap4 = 64;                  // degenerate-ws guard (no OOB)
    int cap = cap4 * 4;

    // ws: [gfill u64*512][binned nbuck*cap][wl16 4096][wr16 4096][xh N*64]
    unsigned long long* gfill = (unsigned long long*)d_ws;
    unsigned int* binned = (unsigned int*)(gfill + MAXBUCK);
    unsigned short* wl16 = (unsigned short*)(binned + (size_t)nbuck * cap);
    unsigned short* wr16 = wl16 + DFEAT * DFEAT;
    unsigned short* xh   = wr16 + DFEAT * DFEAT;

    hipMemsetAsync(gfill, 0, MAXBUCK * sizeof(unsigned long long), stream);

    int nx4 = N * DFEAT / 4;
    int nbin = (E + BCHUNK - 1) / BCHUNK;      // 112
    prep_bin<<<CONVB + nbin, 512, 0, stream>>>(
        x, Wl, Wr, src, dst, xh, wl16, wr16, gfill, binned,
        nx4, E, nbuck, cap, cap4);

    int mg = (nbuck + 7) >> 3;
    sage_fused<<<mg * 32, 256, 0, stream>>>(
        xh, binned, gfill, wl16, wr16, bl, out, N, nbuck, cap, cap4);
}